// Round 2
// baseline (327.866 us; speedup 1.0000x reference)
//
#include <hip/hip_runtime.h>

// AggregationLoss: two-pass segment-sum + per-pixel loss reduction.
// Pass 1: per-batch per-label sums (ksum, rsum, psum[c]) in INT fixed-point
//         (ds_add_u32 / global_atomic_add are native; float atomicAdd is a
//         CAS loop on gfx950 -> 322us stall storm in round 1).
//         R16-REPLICATED LDS tables: dispatch #69 (L3-resident) ran at the
//         same 95us as HBM-fed dispatches -> kernel was ds-atomic-bound
//         (~70 cyc/ds_add from same-address serialization, 64 lanes -> 33
//         slots). 16 copies (stride 198 ints = 6-bank shift/copy, distinct
//         for c=0..15) drop same-address multiplicity to ~1.
// Pass 2: per-pixel Gk gather, hinge-log loss, per-block partial (plain store).
// Pass 3: 1-block finalize reduces partials, divides by num_kernel.

constexpr int NSEG = 33;
constexpr int NCH  = 4;
constexpr int WS_PER_B = NSEG * (NCH + 2);  // 198 ints per batch
constexpr int NREP = 16;                    // LDS table replication factor
constexpr float SIGMA_AGG = 0.5f;
constexpr float QSCALE = 32768.0f;          // 2^15 fixed point
constexpr float QINV   = 1.0f / 32768.0f;

// ws layout (ints): [0, B*198) pass-1 tables, [B*198] numk,
// then (float) partials at int offset 3200.
constexpr int NUMK_OFF = 16 * WS_PER_B;     // 3168
constexpr int PART_OFF = 3200;

__global__ __launch_bounds__(256) void seg_sums_kernel(
    const float* __restrict__ pred, const float* __restrict__ kmask,
    const int* __restrict__ rlab, const int* __restrict__ klab,
    int* __restrict__ ws, int* __restrict__ numk_out,
    int N, int lastB)
{
    const int b = blockIdx.y;
    __shared__ int s_acc[NREP * WS_PER_B];   // 16 copies x 198 ints = 12672 B
    __shared__ int s_maxk;
    for (int j = threadIdx.x; j < NREP * WS_PER_B; j += blockDim.x) s_acc[j] = 0;
    if (threadIdx.x == 0) s_maxk = 0;
    __syncthreads();

    // Each lane privatizes into copy (lane & 15): 64 lanes -> 528 addresses,
    // same-address multiplicity ~1, busiest bank ~4-way (free-ish per m136).
    const int cbase = (threadIdx.x & (NREP - 1)) * WS_PER_B;

    const size_t bN = (size_t)b * N;
    const int Nv = N >> 2;
    const float4* __restrict__ predv = (const float4*)(pred + (size_t)b * NCH * N);
    const float4* __restrict__ kmv   = (const float4*)(kmask + bN);
    const int4*   __restrict__ rlv   = (const int4*)(rlab + bN);
    const int4*   __restrict__ klv   = (const int4*)(klab + bN);

    int mk = 0;
    for (int i = blockIdx.x * blockDim.x + threadIdx.x; i < Nv;
         i += gridDim.x * blockDim.x) {
        float4 km = kmv[i];
        int4   kl = klv[i];
        int4   rl = rlv[i];
        float4 p0 = predv[0 * Nv + i];
        float4 p1 = predv[1 * Nv + i];
        float4 p2 = predv[2 * Nv + i];
        float4 p3 = predv[3 * Nv + i];

        #define PIX(sfx) do {                                                 \
            int kl_ = kl.sfx, rl_ = rl.sfx;                                   \
            int kq = __float2int_rn(km.sfx * QSCALE);                         \
            atomicAdd(&s_acc[cbase + kl_], kq);                               \
            atomicAdd(&s_acc[cbase + NSEG + rl_], kq);                        \
            atomicAdd(&s_acc[cbase + 2 * NSEG + 0 * NSEG + kl_],              \
                      __float2int_rn(p0.sfx * QSCALE));                       \
            atomicAdd(&s_acc[cbase + 2 * NSEG + 1 * NSEG + kl_],              \
                      __float2int_rn(p1.sfx * QSCALE));                       \
            atomicAdd(&s_acc[cbase + 2 * NSEG + 2 * NSEG + kl_],              \
                      __float2int_rn(p2.sfx * QSCALE));                       \
            atomicAdd(&s_acc[cbase + 2 * NSEG + 3 * NSEG + kl_],              \
                      __float2int_rn(p3.sfx * QSCALE));                       \
            mk = max(mk, kl_);                                                \
        } while (0)
        PIX(x); PIX(y); PIX(z); PIX(w);
        #undef PIX
    }
    __syncthreads();

    // Reduce the 16 copies, one global int atomic per slot.
    // Reads are lane-consecutive per copy (2-way max, free); int sums are
    // order-invariant so fixed-point results stay bit-identical.
    int* wsb = ws + b * WS_PER_B;
    for (int j = threadIdx.x; j < WS_PER_B; j += blockDim.x) {
        int v = 0;
        #pragma unroll
        for (int r = 0; r < NREP; ++r) v += s_acc[r * WS_PER_B + j];
        atomicAdd(&wsb[j], v);           // int: native global atomic
    }

    if (b == lastB) {
        atomicMax(&s_maxk, mk);
        __syncthreads();
        if (threadIdx.x == 0) atomicMax(numk_out, s_maxk);
    }
}

__global__ __launch_bounds__(256) void loss_kernel(
    const float* __restrict__ pred, const float* __restrict__ rmask,
    const int* __restrict__ rlab, const int* __restrict__ klab,
    const int* __restrict__ ws, float* __restrict__ partials, int N)
{
    const int b = blockIdx.y;
    __shared__ float s_gk[NCH * NSEG];   // psum[c][s] / (ksum[s]+1); 0 for s==0
    __shared__ float s_rinv[NSEG];       // 1/(rsum[s]+1); slot 0 = 1.0 (rcard=0)
    __shared__ float s_part[4];
    const int* wsb = ws + b * WS_PER_B;
    for (int j = threadIdx.x; j < NSEG; j += blockDim.x) {
        float rs = (float)wsb[NSEG + j] * QINV;
        s_rinv[j] = (j > 0) ? 1.0f / (rs + 1.0f) : 1.0f;
    }
    for (int j = threadIdx.x; j < NCH * NSEG; j += blockDim.x) {
        int s = j % NSEG;
        float ks = (float)wsb[s] * QINV;
        float ps = (float)wsb[2 * NSEG + j] * QINV;
        s_gk[j] = (s > 0) ? ps / (ks + 1.0f) : 0.0f;
    }
    __syncthreads();

    const size_t bN = (size_t)b * N;
    const int Nv = N >> 2;
    const float4* __restrict__ predv = (const float4*)(pred + (size_t)b * NCH * N);
    const float4* __restrict__ rmv   = (const float4*)(rmask + bN);
    const int4*   __restrict__ rlv   = (const int4*)(rlab + bN);
    const int4*   __restrict__ klv   = (const int4*)(klab + bN);

    float acc = 0.0f;
    for (int i = blockIdx.x * blockDim.x + threadIdx.x; i < Nv;
         i += gridDim.x * blockDim.x) {
        float4 rm = rmv[i];
        int4   kl = klv[i];
        int4   rl = rlv[i];
        float4 p0 = predv[0 * Nv + i];
        float4 p1 = predv[1 * Nv + i];
        float4 p2 = predv[2 * Nv + i];
        float4 p3 = predv[3 * Nv + i];

        #define PIX(sfx) do {                                        \
            int kl_ = kl.sfx, rl_ = rl.sfx; float rm_ = rm.sfx;      \
            float d0 = fmaf(p0.sfx, rm_, -s_gk[0 * NSEG + kl_]);     \
            float d1 = fmaf(p1.sfx, rm_, -s_gk[1 * NSEG + kl_]);     \
            float d2 = fmaf(p2.sfx, rm_, -s_gk[2 * NSEG + kl_]);     \
            float d3 = fmaf(p3.sfx, rm_, -s_gk[3 * NSEG + kl_]);     \
            float ss = d0*d0 + d1*d1 + d2*d2 + d3*d3;                \
            float nrm = sqrtf(ss);                                   \
            float dd = fmaxf(nrm - SIGMA_AGG, 0.0f);                 \
            acc += __logf(fmaf(dd, dd, 1.0f)) * s_rinv[rl_];         \
        } while (0)
        PIX(x); PIX(y); PIX(z); PIX(w);
        #undef PIX
    }

    // wave (64-lane) reduce, then cross-wave via LDS; plain store (no atomic)
    for (int off = 32; off > 0; off >>= 1)
        acc += __shfl_down(acc, off);
    const int lane = threadIdx.x & 63;
    const int wid  = threadIdx.x >> 6;
    if (lane == 0) s_part[wid] = acc;
    __syncthreads();
    if (threadIdx.x == 0)
        partials[blockIdx.y * gridDim.x + blockIdx.x] =
            s_part[0] + s_part[1] + s_part[2] + s_part[3];
}

__global__ __launch_bounds__(256) void finalize_kernel(
    const float* __restrict__ partials, const int* __restrict__ numk,
    float* __restrict__ out, int nPart)
{
    __shared__ float s_part[4];
    float a = 0.0f;
    for (int i = threadIdx.x; i < nPart; i += blockDim.x) a += partials[i];
    for (int off = 32; off > 0; off >>= 1)
        a += __shfl_down(a, off);
    if ((threadIdx.x & 63) == 0) s_part[threadIdx.x >> 6] = a;
    __syncthreads();
    if (threadIdx.x == 0)
        out[0] = (s_part[0] + s_part[1] + s_part[2] + s_part[3]) / (float)(*numk);
}

extern "C" void kernel_launch(void* const* d_in, const int* in_sizes, int n_in,
                              void* d_out, int out_size, void* d_ws, size_t ws_size,
                              hipStream_t stream)
{
    const float* pred  = (const float*)d_in[0];
    const float* rmask = (const float*)d_in[1];
    const float* kmask = (const float*)d_in[2];
    const int*   rlab  = (const int*)d_in[3];
    const int*   klab  = (const int*)d_in[4];
    float* out = (float*)d_out;

    const int B = 16;
    const int N = in_sizes[1] / B;   // H*W per batch

    int* wsi = (int*)d_ws;
    int* numk = wsi + NUMK_OFF;
    float* partials = (float*)(wsi + PART_OFF);

    // ws is poisoned 0xAA before every launch — zero the accumulator tables.
    hipMemsetAsync(d_ws, 0, (size_t)(NUMK_OFF + 1) * sizeof(int), stream);

    dim3 block(256);
    dim3 grid(256, B);   // 4096 blocks
    seg_sums_kernel<<<grid, block, 0, stream>>>(pred, kmask, rlab, klab, wsi, numk, N, B - 1);
    loss_kernel<<<grid, block, 0, stream>>>(pred, rmask, rlab, klab, wsi, partials, N);
    finalize_kernel<<<dim3(1), block, 0, stream>>>(partials, numk, out, 256 * B);
}

// Round 3
// 326.921 us; speedup vs baseline: 1.0029x; 1.0029x over previous
//
#include <hip/hip_runtime.h>

// AggregationLoss: two-pass segment-sum + per-pixel loss reduction.
// Pass 1 (seg_sums): R2 post-mortem showed ds_atomic cost is PER-INSTRUCTION
//         (~71 cyc/wave-instr, invariant to 16x address replication and to
//         L3-vs-HBM sourcing) -> lane-serialized LDS atomic unit. Fix: NO
//         atomics. 6 streams (p0..p3@klab, ksum@klab, rsum@rlab) assigned to
//         the 6 waves of a 384-thread block; each THREAD owns a private
//         33-int LDS table updated with plain ds_read+add+ds_write (~13 cyc).
//         384*33*4B = 50.7 KB -> 3 blocks/CU (18 waves). Block-end: 198
//         cross-thread sums -> one global int atomicAdd each (order-invariant
//         integer adds keep results bit-identical).
// Pass 2: per-pixel Gk gather, hinge-log loss, per-block partial (plain store).
// Pass 3: 1-block finalize reduces partials, divides by num_kernel.

constexpr int NSEG = 33;
constexpr int NCH  = 4;
constexpr int WS_PER_B = NSEG * (NCH + 2);  // 198 ints per batch
constexpr int NWAVE = 6;                    // streams: p0,p1,p2,p3,ksum,rsum
constexpr int NTHR  = NWAVE * 64;           // 384 threads
constexpr float SIGMA_AGG = 0.5f;
constexpr float QSCALE = 32768.0f;          // 2^15 fixed point
constexpr float QINV   = 1.0f / 32768.0f;

// ws layout (ints): [0, B*198) pass-1 tables, [B*198] numk,
// then (float) partials at int offset 3200.
constexpr int NUMK_OFF = 16 * WS_PER_B;     // 3168
constexpr int PART_OFF = 3200;

__global__ __launch_bounds__(NTHR) void seg_sums_kernel(
    const float* __restrict__ pred, const float* __restrict__ kmask,
    const int* __restrict__ rlab, const int* __restrict__ klab,
    int* __restrict__ ws, int* __restrict__ numk_out,
    int N, int lastB)
{
    __shared__ int s_tbl[NTHR * NSEG];       // 50688 B: one 33-int table/thread
    int* mytbl = s_tbl + threadIdx.x * NSEG;
    #pragma unroll
    for (int j = 0; j < NSEG; ++j) mytbl[j] = 0;
    // no barrier needed: each thread touches only its own table until reduce

    const int b    = blockIdx.y;
    const int wv   = threadIdx.x >> 6;       // 0..5 stream id (wave-uniform)
    const int lane = threadIdx.x & 63;
    const size_t bN = (size_t)b * N;
    const int Nv = N >> 2;

    // wave 0-3: pred channel wv; wave 4,5: kmask. wave 5 keys by rlab.
    const float4* __restrict__ val4 =
        (wv < 4) ? ((const float4*)(pred + (size_t)b * NCH * N)) + (size_t)wv * Nv
                 : (const float4*)(kmask + bN);
    const int4* __restrict__ lab4 =
        (wv == 5) ? (const int4*)(rlab + bN) : (const int4*)(klab + bN);

    int mk = 0;
    for (int u = blockIdx.x * 64 + lane; u < Nv; u += gridDim.x * 64) {
        float4 v = val4[u];
        int4   L = lab4[u];
        // Private-table RMW; compiler serializes possible L.x==L.y aliasing,
        // which is exactly the correct behavior.
        mytbl[L.x] += __float2int_rn(v.x * QSCALE);
        mytbl[L.y] += __float2int_rn(v.y * QSCALE);
        mytbl[L.z] += __float2int_rn(v.z * QSCALE);
        mytbl[L.w] += __float2int_rn(v.w * QSCALE);
        if (wv == 4) mk = max(mk, max(max(L.x, L.y), max(L.z, L.w)));
    }
    __syncthreads();

    // Reduce 64 per-thread tables per stream -> 198 outputs -> global atomics.
    if (threadIdx.x < NWAVE * NSEG) {        // 198 < 384
        const int s = threadIdx.x / NSEG;
        const int j = threadIdx.x - s * NSEG;
        int v = 0;
        #pragma unroll 8
        for (int l = 0; l < 64; ++l) v += s_tbl[(s * 64 + l) * NSEG + j];
        // ws layout per batch: [ksum(33) | rsum(33) | psum[c][33]*4]
        const int off = (s < 4) ? (2 * NSEG + s * NSEG + j)
                                : ((s == 4) ? j : NSEG + j);
        atomicAdd(&ws[b * WS_PER_B + off], v);   // int: native global atomic
    }

    if (b == lastB && wv == 4) {
        for (int off = 32; off > 0; off >>= 1)
            mk = max(mk, __shfl_down(mk, off));
        if (lane == 0) atomicMax(numk_out, mk);
    }
}

__global__ __launch_bounds__(256) void loss_kernel(
    const float* __restrict__ pred, const float* __restrict__ rmask,
    const int* __restrict__ rlab, const int* __restrict__ klab,
    const int* __restrict__ ws, float* __restrict__ partials, int N)
{
    const int b = blockIdx.y;
    __shared__ float s_gk[NCH * NSEG];   // psum[c][s] / (ksum[s]+1); 0 for s==0
    __shared__ float s_rinv[NSEG];       // 1/(rsum[s]+1); slot 0 = 1.0 (rcard=0)
    __shared__ float s_part[4];
    const int* wsb = ws + b * WS_PER_B;
    for (int j = threadIdx.x; j < NSEG; j += blockDim.x) {
        float rs = (float)wsb[NSEG + j] * QINV;
        s_rinv[j] = (j > 0) ? 1.0f / (rs + 1.0f) : 1.0f;
    }
    for (int j = threadIdx.x; j < NCH * NSEG; j += blockDim.x) {
        int s = j % NSEG;
        float ks = (float)wsb[s] * QINV;
        float ps = (float)wsb[2 * NSEG + j] * QINV;
        s_gk[j] = (s > 0) ? ps / (ks + 1.0f) : 0.0f;
    }
    __syncthreads();

    const size_t bN = (size_t)b * N;
    const int Nv = N >> 2;
    const float4* __restrict__ predv = (const float4*)(pred + (size_t)b * NCH * N);
    const float4* __restrict__ rmv   = (const float4*)(rmask + bN);
    const int4*   __restrict__ rlv   = (const int4*)(rlab + bN);
    const int4*   __restrict__ klv   = (const int4*)(klab + bN);

    float acc = 0.0f;
    for (int i = blockIdx.x * blockDim.x + threadIdx.x; i < Nv;
         i += gridDim.x * blockDim.x) {
        float4 rm = rmv[i];
        int4   kl = klv[i];
        int4   rl = rlv[i];
        float4 p0 = predv[0 * Nv + i];
        float4 p1 = predv[1 * Nv + i];
        float4 p2 = predv[2 * Nv + i];
        float4 p3 = predv[3 * Nv + i];

        #define PIX(sfx) do {                                        \
            int kl_ = kl.sfx, rl_ = rl.sfx; float rm_ = rm.sfx;      \
            float d0 = fmaf(p0.sfx, rm_, -s_gk[0 * NSEG + kl_]);     \
            float d1 = fmaf(p1.sfx, rm_, -s_gk[1 * NSEG + kl_]);     \
            float d2 = fmaf(p2.sfx, rm_, -s_gk[2 * NSEG + kl_]);     \
            float d3 = fmaf(p3.sfx, rm_, -s_gk[3 * NSEG + kl_]);     \
            float ss = d0*d0 + d1*d1 + d2*d2 + d3*d3;                \
            float nrm = sqrtf(ss);                                   \
            float dd = fmaxf(nrm - SIGMA_AGG, 0.0f);                 \
            acc += __logf(fmaf(dd, dd, 1.0f)) * s_rinv[rl_];         \
        } while (0)
        PIX(x); PIX(y); PIX(z); PIX(w);
        #undef PIX
    }

    // wave (64-lane) reduce, then cross-wave via LDS; plain store (no atomic)
    for (int off = 32; off > 0; off >>= 1)
        acc += __shfl_down(acc, off);
    const int lane = threadIdx.x & 63;
    const int wid  = threadIdx.x >> 6;
    if (lane == 0) s_part[wid] = acc;
    __syncthreads();
    if (threadIdx.x == 0)
        partials[blockIdx.y * gridDim.x + blockIdx.x] =
            s_part[0] + s_part[1] + s_part[2] + s_part[3];
}

__global__ __launch_bounds__(256) void finalize_kernel(
    const float* __restrict__ partials, const int* __restrict__ numk,
    float* __restrict__ out, int nPart)
{
    __shared__ float s_part[4];
    float a = 0.0f;
    for (int i = threadIdx.x; i < nPart; i += blockDim.x) a += partials[i];
    for (int off = 32; off > 0; off >>= 1)
        a += __shfl_down(a, off);
    if ((threadIdx.x & 63) == 0) s_part[threadIdx.x >> 6] = a;
    __syncthreads();
    if (threadIdx.x == 0)
        out[0] = (s_part[0] + s_part[1] + s_part[2] + s_part[3]) / (float)(*numk);
}

extern "C" void kernel_launch(void* const* d_in, const int* in_sizes, int n_in,
                              void* d_out, int out_size, void* d_ws, size_t ws_size,
                              hipStream_t stream)
{
    const float* pred  = (const float*)d_in[0];
    const float* rmask = (const float*)d_in[1];
    const float* kmask = (const float*)d_in[2];
    const int*   rlab  = (const int*)d_in[3];
    const int*   klab  = (const int*)d_in[4];
    float* out = (float*)d_out;

    const int B = 16;
    const int N = in_sizes[1] / B;   // H*W per batch

    int* wsi = (int*)d_ws;
    int* numk = wsi + NUMK_OFF;
    float* partials = (float*)(wsi + PART_OFF);

    // ws is poisoned 0xAA before every launch — zero the accumulator tables.
    hipMemsetAsync(d_ws, 0, (size_t)(NUMK_OFF + 1) * sizeof(int), stream);

    // seg_sums: 384-thread blocks (6 stream-waves), 3 blocks/CU (50.7 KB LDS);
    // grid.x=96 -> 1536 blocks = exactly 2 residency rounds.
    seg_sums_kernel<<<dim3(96, B), dim3(NTHR), 0, stream>>>(
        pred, kmask, rlab, klab, wsi, numk, N, B - 1);
    loss_kernel<<<dim3(256, B), dim3(256), 0, stream>>>(
        pred, rmask, rlab, klab, wsi, partials, N);
    finalize_kernel<<<dim3(1), dim3(256), 0, stream>>>(partials, numk, out, 256 * B);
}